// Round 14
// baseline (85.145 us; speedup 1.0000x reference)
//
#include <hip/hip_runtime.h>
#include <math.h>

#define NN 8192
#define DIM 128
#define NQ 256        // 32-row strips
#define NP 8
#define NBLK (NQ * NP)   // 2048
#define NCT 32           // 256-col tiles

typedef short bf16x8 __attribute__((ext_vector_type(8)));
typedef float f32x4 __attribute__((ext_vector_type(4)));

__device__ inline unsigned short f2bf(float x) {
    unsigned u = __float_as_uint(x);
    unsigned r = u + 0x7FFFu + ((u >> 16) & 1u);  // RNE
    return (unsigned short)(r >> 16);
}
__device__ inline float bf2f(unsigned short h) {
    return __uint_as_float(((unsigned)h) << 16);
}

// ---------------------------------------------------------------------------
// Kernel 0: pack mapping into MFMA-fragment-order bf16 chunks (1KB/wave-load).
// ---------------------------------------------------------------------------
__global__ void pack_kernel(const float* __restrict__ m, unsigned short* __restrict__ buf2) {
    const int t = threadIdx.x, l = t & 63;
    const int W = blockIdx.x * 4 + (t >> 6);
    const int g = W >> 2, kq = W & 3;
    const int row = g * 16 + (l & 15);
    const int k0 = kq * 32 + (l >> 4) * 8;
    const float* src = m + (size_t)row * DIM + k0;
    float4 v0 = *reinterpret_cast<const float4*>(src);
    float4 v1 = *reinterpret_cast<const float4*>(src + 4);
    float f[8] = {v0.x, v0.y, v0.z, v0.w, v1.x, v1.y, v1.z, v1.w};
    union { ushort4 u4[2]; unsigned short us[8]; } o;
#pragma unroll
    for (int q = 0; q < 8; ++q) o.us[q] = f2bf(f[q]);
    unsigned short* dst = buf2 + (size_t)W * 512 + l * 8;
    *reinterpret_cast<ushort4*>(dst) = o.u4[0];
    *reinterpret_cast<ushort4*>(dst + 4) = o.u4[1];
}

// ---------------------------------------------------------------------------
// Kernel 1: exact fp32 row norms
// ---------------------------------------------------------------------------
__global__ void sq_kernel(const float* __restrict__ mapping, float* __restrict__ sq) {
    int i = blockIdx.x * blockDim.x + threadIdx.x;
    if (i < NN) {
        const float4* row = reinterpret_cast<const float4*>(mapping + (size_t)i * DIM);
        float s = 0.f;
#pragma unroll
        for (int q = 0; q < DIM / 4; ++q) {
            float4 v = row[q];
            s += v.x * v.x + v.y * v.y + v.z * v.z + v.w * v.w;
        }
        sq[i] = s;
    }
}

// ---------------------------------------------------------------------------
// Kernel 2: P/C waves + WIDE tiles (32 rows x 256 cols -> 1KB/row per visit).
// Block (q,p): rows 32q..+31; col tiles c = q/8+p, +8, .. (<32).
// Waves 0-1 (producers): MFMA d-tile -> LDS ring (2 slots).
// Waves 2-3 (consumers): pure D stream, 8 rows x 128B per inst, 8 insts/row
// consecutive -> 1KB linear bursts; half-tile reg pipeline across the single
// raw s_barrier per tile. Consumer FIFO contains ONLY D loads.
// ---------------------------------------------------------------------------
__global__ __launch_bounds__(256, 4) void dist_kernel(const unsigned short* __restrict__ buf2,
                                                      const float* __restrict__ D,
                                                      const float* __restrict__ sq,
                                                      float* __restrict__ partials) {
    __shared__ __align__(16) unsigned short dts[2][32][264];  // 33KB ring
    __shared__ float wred[4];

    const int t = threadIdx.x, l = t & 63, w = t >> 6;
    const int b = blockIdx.x;
    const int q = b >> 3, p = b & 7;
    const int c0 = (q >> 3) + p;
    float psum = 0.f;

    if (c0 < NCT) {
        const int nt = ((NCT - 1 - c0) >> 3) + 1;
        const int l15 = l & 15, hi = l >> 4;

        if (w < 2) {
            // ========================= PRODUCER =========================
            const int i_row = q * 32 + w * 16 + l15;
            bf16x8 af[4];
#pragma unroll
            for (int kq = 0; kq < 4; ++kq)
                af[kq] = *(const bf16x8*)(buf2 + (size_t)((q * 2 + w) * 4 + kq) * 512 + l * 8);
            const float sa = sq[i_row];

            for (int tt = 0; tt < nt; ++tt) {
                const int c = c0 + tt * 8;
                unsigned short* slot = &dts[tt & 1][0][0];
#pragma unroll
                for (int s = 0; s < 16; ++s) {
                    bf16x8 bfr[4];
#pragma unroll
                    for (int kq = 0; kq < 4; ++kq)
                        bfr[kq] = *(const bf16x8*)(buf2 + (size_t)((c * 16 + s) * 4 + kq) * 512 + l * 8);
                    f32x4 sb = *(const f32x4*)(sq + c * 256 + s * 16 + hi * 4);
                    f32x4 acc = {};
#pragma unroll
                    for (int kq = 0; kq < 4; ++kq)
                        acc = __builtin_amdgcn_mfma_f32_16x16x32_bf16(bfr[kq], af[kq], acc, 0, 0, 0);
                    ushort4 o;
                    unsigned short* op = (unsigned short*)&o;
#pragma unroll
                    for (int r = 0; r < 4; ++r) {
                        float d2 = fmaf(-2.f, acc[r], sa + sb[r]);
                        op[r] = f2bf(sqrtf(fmaxf(d2, 0.f)));
                    }
                    *reinterpret_cast<ushort4*>(slot + (w * 16 + l15) * 264 + s * 16 + hi * 4) = o;
                }
                asm volatile("s_waitcnt lgkmcnt(0)" ::: "memory");
                __builtin_amdgcn_sched_barrier(0);
                __builtin_amdgcn_s_barrier();
            }
        } else {
            // ========================= CONSUMER =========================
            const int cw = w - 2;
            const int r8 = l & 7, k16 = l >> 3;          // row-in-group, 16B chunk
            const int row_loc0 = cw * 16 + r8;           // rg0 row (in tile)
            const int i0 = q * 32 + row_loc0;            // global row, rg0
            const int i1 = i0 + 8;                       // global row, rg1
            const float* Dr0 = D + (size_t)i0 * NN + k16 * 4;
            const float* Dr1 = D + (size_t)i1 * NN + k16 * 4;
            const int cq = q >> 3;

            f32x4 d0[8], d1[8];   // half-tile D buffers (static index only)

            auto issue0 = [&](int c) {
#pragma unroll
                for (int k = 0; k < 8; ++k)
                    d0[k] = *(const f32x4*)(Dr0 + c * 256 + k * 32);
            };
            auto issue1 = [&](int c) {
#pragma unroll
                for (int k = 0; k < 8; ++k)
                    d1[k] = *(const f32x4*)(Dr1 + c * 256 + k * 32);
            };
            auto consume = [&](int c, int rg, const f32x4(&dd)[8]) {
                const unsigned short* slot = &dts[0][0][0] + (size_t)( ((c - c0) >> 3) & 1 ) * 32 * 264;
                const int row_loc = cw * 16 + rg * 8 + r8;
                const int i_g = q * 32 + row_loc;
                const bool diag = (c == cq);
#pragma unroll
                for (int k = 0; k < 8; ++k) {
                    ushort4 dv = *reinterpret_cast<const ushort4*>(
                        &dts[0][0][0] + (slot - &dts[0][0][0]) + row_loc * 264 + k * 32 + k16 * 4);
                    const unsigned short* dp = (const unsigned short*)&dv;
#pragma unroll
                    for (int r = 0; r < 4; ++r) {
                        float Dv = dd[k][r];
                        float ratio = __fdividef(fabsf(bf2f(dp[r]) - Dv), Dv);
                        if (!diag) psum += ratio;
                        else {
                            const int j = c * 256 + k * 32 + k16 * 4 + r;
                            if (j > i_g) psum += ratio;
                        }
                    }
                }
            };

            // prologue: D(tile 0) fully in flight before first barrier
            issue0(c0);
            issue1(c0);
            __builtin_amdgcn_s_barrier();   // matches producer fill(0)

            for (int tt = 0; tt < nt; ++tt) {
                const int c = c0 + tt * 8;
                const int cnext = c + 8;
                consume(c, 0, d0);
                if (tt + 1 < nt) issue0(cnext);
                consume(c, 1, d1);
                if (tt + 1 < nt) issue1(cnext);
                if (tt + 1 < nt) __builtin_amdgcn_s_barrier();  // matches fill(tt+1)
            }
        }
    }

    // ---- deterministic block reduction ----
    for (int off = 32; off > 0; off >>= 1) psum += __shfl_down(psum, off, 64);
    __syncthreads();
    if (l == 0) wred[w] = psum;
    __syncthreads();
    if (t == 0) partials[b] = 2.f * ((wred[0] + wred[1]) + (wred[2] + wred[3]));
}

// ---------------------------------------------------------------------------
// Kernel 3: deterministic final reduction
// ---------------------------------------------------------------------------
__global__ void reduce_kernel(const float* __restrict__ partials, float* __restrict__ out) {
    __shared__ double sm[256];
    const int t = threadIdx.x;
    double s = 0.0;
    for (int i = t; i < NBLK; i += 256) s += (double)partials[i];
    sm[t] = s;
    __syncthreads();
    for (int off = 128; off > 0; off >>= 1) {
        if (t < off) sm[t] += sm[t + off];
        __syncthreads();
    }
    if (t == 0) out[0] = (float)(sm[0] / ((double)NN * (double)NN - (double)NN));
}

// ---------------------------------------------------------------------------
extern "C" void kernel_launch(void* const* d_in, const int* in_sizes, int n_in,
                              void* d_out, int out_size, void* d_ws, size_t ws_size,
                              hipStream_t stream) {
    const float* mapping = (const float*)d_in[0];
    const float* D       = (const float*)d_in[1];
    float* out = (float*)d_out;

    unsigned short* buf2 = (unsigned short*)d_ws;        // NN*DIM bf16 = 2 MiB
    float* sq            = (float*)(buf2 + NN * DIM);    // NN floats
    float* partials      = sq + NN;                      // NBLK floats

    pack_kernel<<<512, 256, 0, stream>>>(mapping, buf2);
    sq_kernel<<<NN / 256, 256, 0, stream>>>(mapping, sq);
    dist_kernel<<<NBLK, 256, 0, stream>>>(buf2, D, sq, partials);
    reduce_kernel<<<1, 256, 0, stream>>>(partials, out);
}

// Round 15
// 77.427 us; speedup vs baseline: 1.0997x; 1.0997x over previous
//
#include <hip/hip_runtime.h>
#include <math.h>

#define NN 8192
#define DIM 128
#define NBLK 2048   // (q 0..127) x (p 0..15)

typedef short bf16x8 __attribute__((ext_vector_type(8)));
typedef float f32x4 __attribute__((ext_vector_type(4)));

__device__ inline unsigned short f2bf(float x) {
    unsigned u = __float_as_uint(x);
    unsigned r = u + 0x7FFFu + ((u >> 16) & 1u);  // RNE
    return (unsigned short)(r >> 16);
}
__device__ inline float bf2f(unsigned short h) {
    return __uint_as_float(((unsigned)h) << 16);
}

// ---------------------------------------------------------------------------
// Kernel 0: pack mapping into MFMA-fragment-order bf16 chunks (1KB/wave-load).
// ---------------------------------------------------------------------------
__global__ void pack_kernel(const float* __restrict__ m, unsigned short* __restrict__ buf2) {
    const int t = threadIdx.x, l = t & 63;
    const int W = blockIdx.x * 4 + (t >> 6);
    const int g = W >> 2, kq = W & 3;
    const int row = g * 16 + (l & 15);
    const int k0 = kq * 32 + (l >> 4) * 8;
    const float* src = m + (size_t)row * DIM + k0;
    float4 v0 = *reinterpret_cast<const float4*>(src);
    float4 v1 = *reinterpret_cast<const float4*>(src + 4);
    float f[8] = {v0.x, v0.y, v0.z, v0.w, v1.x, v1.y, v1.z, v1.w};
    union { ushort4 u4[2]; unsigned short us[8]; } o;
#pragma unroll
    for (int q = 0; q < 8; ++q) o.us[q] = f2bf(f[q]);
    unsigned short* dst = buf2 + (size_t)W * 512 + l * 8;
    *reinterpret_cast<ushort4*>(dst) = o.u4[0];
    *reinterpret_cast<ushort4*>(dst + 4) = o.u4[1];
}

// ---------------------------------------------------------------------------
// Kernel 1: exact fp32 row norms
// ---------------------------------------------------------------------------
__global__ void sq_kernel(const float* __restrict__ mapping, float* __restrict__ sq) {
    int i = blockIdx.x * blockDim.x + threadIdx.x;
    if (i < NN) {
        const float4* row = reinterpret_cast<const float4*>(mapping + (size_t)i * DIM);
        float s = 0.f;
#pragma unroll
        for (int q = 0; q < DIM / 4; ++q) {
            float4 v = row[q];
            s += v.x * v.x + v.y * v.y + v.z * v.z + v.w * v.w;
        }
        sq[i] = s;
    }
}

// ---------------------------------------------------------------------------
// Kernel 2: r13 producer/consumer structure, ONE change: consumer D loads are
// NON-TEMPORAL (nt). D (268MB > 256MB L3) is a pure stream; nt keeps it from
// evicting the L2-resident buf2 (B fragments) and from thrashing L3 — the
// r11 diag showed B-alone and D-alone are each ~22µs but fused is ~60µs:
// cache interference, not scheduling, is the hypothesis under test.
// ---------------------------------------------------------------------------
__global__ __launch_bounds__(512, 4) void dist_kernel(const unsigned short* __restrict__ buf2,
                                                      const float* __restrict__ D,
                                                      const float* __restrict__ sq,
                                                      float* __restrict__ partials) {
    __shared__ __align__(16) char dtile[2][64 * 144];  // bf16 d, 144B row pitch
    __shared__ float wred[8];

    const int t = threadIdx.x, l = t & 63, w = t >> 6;
    const int b = blockIdx.x;
    const int q = b >> 4, p = b & 15;
    const int cj0 = q + p;
    float psum = 0.f;

    if (cj0 < 128) {
        const int nt = (128 - cj0 + 15) >> 4;
        const int l15 = l & 15, hi = l >> 4;
        const int colq = hi * 4;
        const int strip = w & 3;
        const int i_row = q * 64 + strip * 16 + l15;
        const int ldsoff = (strip * 16 + l15) * 144 + hi * 8;  // + s*32

        if (w < 4) {
            // ========================= PRODUCER =========================
            bf16x8 af[4];
#pragma unroll
            for (int kq = 0; kq < 4; ++kq)
                af[kq] = *(const bf16x8*)(buf2 + (size_t)((q * 4 + strip) * 4 + kq) * 512 + l * 8);
            const float sa = sq[i_row];

            for (int tt = 0; tt < nt; ++tt) {
                const int cj = cj0 + tt * 16;
                char* slot = &dtile[tt & 1][0];
#pragma unroll
                for (int s = 0; s < 4; ++s) {
                    bf16x8 bfr[4];
#pragma unroll
                    for (int kq = 0; kq < 4; ++kq)
                        bfr[kq] = *(const bf16x8*)(buf2 + (size_t)((cj * 4 + s) * 4 + kq) * 512 + l * 8);
                    f32x4 sb = *(const f32x4*)(sq + cj * 64 + s * 16 + colq);
                    f32x4 acc = {};
#pragma unroll
                    for (int kq = 0; kq < 4; ++kq)
                        acc = __builtin_amdgcn_mfma_f32_16x16x32_bf16(bfr[kq], af[kq], acc, 0, 0, 0);
                    ushort4 o;
                    unsigned short* op = (unsigned short*)&o;
#pragma unroll
                    for (int r = 0; r < 4; ++r) {
                        float d2 = fmaf(-2.f, acc[r], sa + sb[r]);
                        op[r] = f2bf(sqrtf(fmaxf(d2, 0.f)));
                    }
                    *reinterpret_cast<ushort4*>(slot + ldsoff + s * 32) = o;
                }
                asm volatile("s_waitcnt lgkmcnt(0)" ::: "memory");
                __builtin_amdgcn_sched_barrier(0);
                __builtin_amdgcn_s_barrier();
            }
        } else {
            // ========================= CONSUMER =========================
            const float* Drow = D + (size_t)i_row * NN;

            auto consume = [&](int tile, const f32x4(&dc)[4]) {
                const int cj = cj0 + tile * 16;
                const char* slot = &dtile[tile & 1][0];
                if (cj != q) {
#pragma unroll
                    for (int s = 0; s < 4; ++s) {
                        ushort4 o = *reinterpret_cast<const ushort4*>(slot + ldsoff + s * 32);
                        const unsigned short* op = (const unsigned short*)&o;
#pragma unroll
                        for (int r = 0; r < 4; ++r) {
                            float Dv = dc[s][r];
                            psum += __fdividef(fabsf(bf2f(op[r]) - Dv), Dv);
                        }
                    }
                } else {
#pragma unroll
                    for (int s = 0; s < 4; ++s) {
                        ushort4 o = *reinterpret_cast<const ushort4*>(slot + ldsoff + s * 32);
                        const unsigned short* op = (const unsigned short*)&o;
#pragma unroll
                        for (int r = 0; r < 4; ++r) {
                            const int j = cj * 64 + s * 16 + colq + r;
                            if (j > i_row) {
                                float Dv = dc[s][r];
                                psum += __fdividef(fabsf(bf2f(op[r]) - Dv), Dv);
                            }
                        }
                    }
                }
            };

            f32x4 dA[4], dB[4];
#pragma unroll
            for (int s = 0; s < 4; ++s)
                dA[s] = __builtin_nontemporal_load(
                    (const f32x4*)(Drow + cj0 * 64 + s * 16 + colq));
            __builtin_amdgcn_s_barrier();

            bool cur_a = true;
            for (int tt = 1; tt < nt; ++tt) {
                const int cj = cj0 + tt * 16;
                if (cur_a) {
#pragma unroll
                    for (int s = 0; s < 4; ++s)
                        dB[s] = __builtin_nontemporal_load(
                            (const f32x4*)(Drow + cj * 64 + s * 16 + colq));
                    consume(tt - 1, dA);
                } else {
#pragma unroll
                    for (int s = 0; s < 4; ++s)
                        dA[s] = __builtin_nontemporal_load(
                            (const f32x4*)(Drow + cj * 64 + s * 16 + colq));
                    consume(tt - 1, dB);
                }
                cur_a = !cur_a;
                __builtin_amdgcn_s_barrier();
            }
            if (cur_a) consume(nt - 1, dA);
            else       consume(nt - 1, dB);
        }
    }

    // ---- deterministic block reduction (8 waves; producers contribute 0) ----
    for (int off = 32; off > 0; off >>= 1) psum += __shfl_down(psum, off, 64);
    __syncthreads();
    if (l == 0) wred[w] = psum;
    __syncthreads();
    if (t == 0) {
        float s = 0.f;
#pragma unroll
        for (int k = 0; k < 8; ++k) s += wred[k];
        partials[b] = 2.f * s;
    }
}

// ---------------------------------------------------------------------------
// Kernel 3: deterministic final reduction
// ---------------------------------------------------------------------------
__global__ void reduce_kernel(const float* __restrict__ partials, float* __restrict__ out) {
    __shared__ double sm[256];
    const int t = threadIdx.x;
    double s = 0.0;
    for (int i = t; i < NBLK; i += 256) s += (double)partials[i];
    sm[t] = s;
    __syncthreads();
    for (int off = 128; off > 0; off >>= 1) {
        if (t < off) sm[t] += sm[t + off];
        __syncthreads();
    }
    if (t == 0) out[0] = (float)(sm[0] / ((double)NN * (double)NN - (double)NN));
}

// ---------------------------------------------------------------------------
extern "C" void kernel_launch(void* const* d_in, const int* in_sizes, int n_in,
                              void* d_out, int out_size, void* d_ws, size_t ws_size,
                              hipStream_t stream) {
    const float* mapping = (const float*)d_in[0];
    const float* D       = (const float*)d_in[1];
    float* out = (float*)d_out;

    unsigned short* buf2 = (unsigned short*)d_ws;        // NN*DIM bf16 = 2 MiB
    float* sq            = (float*)(buf2 + NN * DIM);    // NN floats
    float* partials      = sq + NN;                      // NBLK floats

    pack_kernel<<<512, 256, 0, stream>>>(mapping, buf2);
    sq_kernel<<<NN / 256, 256, 0, stream>>>(mapping, sq);
    dist_kernel<<<NBLK, 512, 0, stream>>>(buf2, D, sq, partials);
    reduce_kernel<<<1, 256, 0, stream>>>(partials, out);
}

// Round 16
// 68.568 us; speedup vs baseline: 1.2418x; 1.1292x over previous
//
#include <hip/hip_runtime.h>
#include <math.h>

#define NN 8192
#define DIM 128
#define NBLK 2048   // (q 0..127) x (p 0..15)

typedef short bf16x8 __attribute__((ext_vector_type(8)));
typedef float f32x4 __attribute__((ext_vector_type(4)));

__device__ inline unsigned short f2bf(float x) {
    unsigned u = __float_as_uint(x);
    unsigned r = u + 0x7FFFu + ((u >> 16) & 1u);  // RNE
    return (unsigned short)(r >> 16);
}
__device__ inline float bf2f(unsigned short h) {
    return __uint_as_float(((unsigned)h) << 16);
}

// ---------------------------------------------------------------------------
// Kernel 0: pack mapping into MFMA-fragment-order bf16 chunks (1KB/wave-load).
// ---------------------------------------------------------------------------
__global__ void pack_kernel(const float* __restrict__ m, unsigned short* __restrict__ buf2) {
    const int t = threadIdx.x, l = t & 63;
    const int W = blockIdx.x * 4 + (t >> 6);
    const int g = W >> 2, kq = W & 3;
    const int row = g * 16 + (l & 15);
    const int k0 = kq * 32 + (l >> 4) * 8;
    const float* src = m + (size_t)row * DIM + k0;
    float4 v0 = *reinterpret_cast<const float4*>(src);
    float4 v1 = *reinterpret_cast<const float4*>(src + 4);
    float f[8] = {v0.x, v0.y, v0.z, v0.w, v1.x, v1.y, v1.z, v1.w};
    union { ushort4 u4[2]; unsigned short us[8]; } o;
#pragma unroll
    for (int q = 0; q < 8; ++q) o.us[q] = f2bf(f[q]);
    unsigned short* dst = buf2 + (size_t)W * 512 + l * 8;
    *reinterpret_cast<ushort4*>(dst) = o.u4[0];
    *reinterpret_cast<ushort4*>(dst + 4) = o.u4[1];
}

// ---------------------------------------------------------------------------
// Kernel 1: exact fp32 row norms
// ---------------------------------------------------------------------------
__global__ void sq_kernel(const float* __restrict__ mapping, float* __restrict__ sq) {
    int i = blockIdx.x * blockDim.x + threadIdx.x;
    if (i < NN) {
        const float4* row = reinterpret_cast<const float4*>(mapping + (size_t)i * DIM);
        float s = 0.f;
#pragma unroll
        for (int q = 0; q < DIM / 4; ++q) {
            float4 v = row[q];
            s += v.x * v.x + v.y * v.y + v.z * v.z + v.w * v.w;
        }
        sq[i] = s;
    }
}

// ---------------------------------------------------------------------------
// Kernel 2: r13 producer/consumer, with (1) 4-slot LDS ring + barrier every
// 2 tiles (half the rendezvous, 2-tile producer run-ahead, D prefetch rides
// across raw s_barrier), (2) 3 blocks/CU (launch_bounds(512,6)) for 12
// consumer D-streams per CU. Slot safety: consumer reads slots {2k,2k+1}&3
// while producer writes {2k+2,2k+3}&3 — disjoint mod 4.
// ---------------------------------------------------------------------------
__global__ __launch_bounds__(512, 6) void dist_kernel(const unsigned short* __restrict__ buf2,
                                                      const float* __restrict__ D,
                                                      const float* __restrict__ sq,
                                                      float* __restrict__ partials) {
    __shared__ __align__(16) char dtile[4][64 * 144];  // 4-slot ring, 36.9KB
    __shared__ float wred[8];

    const int t = threadIdx.x, l = t & 63, w = t >> 6;
    const int b = blockIdx.x;
    const int q = b >> 4, p = b & 15;
    const int cj0 = q + p;
    float psum = 0.f;

    if (cj0 < 128) {
        const int nt = (128 - cj0 + 15) >> 4;
        const int l15 = l & 15, hi = l >> 4;
        const int colq = hi * 4;
        const int strip = w & 3;
        const int i_row = q * 64 + strip * 16 + l15;
        const int ldsoff = (strip * 16 + l15) * 144 + hi * 8;  // + s*32

        if (w < 4) {
            // ========================= PRODUCER =========================
            bf16x8 af[4];
#pragma unroll
            for (int kq = 0; kq < 4; ++kq)
                af[kq] = *(const bf16x8*)(buf2 + (size_t)((q * 4 + strip) * 4 + kq) * 512 + l * 8);
            const float sa = sq[i_row];

            for (int tt = 0; tt < nt; ++tt) {
                const int cj = cj0 + tt * 16;
                char* slot = &dtile[tt & 3][0];
#pragma unroll
                for (int s = 0; s < 4; ++s) {
                    bf16x8 bfr[4];
#pragma unroll
                    for (int kq = 0; kq < 4; ++kq)
                        bfr[kq] = *(const bf16x8*)(buf2 + (size_t)((cj * 4 + s) * 4 + kq) * 512 + l * 8);
                    f32x4 sb = *(const f32x4*)(sq + cj * 64 + s * 16 + colq);
                    f32x4 acc = {};
#pragma unroll
                    for (int kq = 0; kq < 4; ++kq)
                        acc = __builtin_amdgcn_mfma_f32_16x16x32_bf16(bfr[kq], af[kq], acc, 0, 0, 0);
                    ushort4 o;
                    unsigned short* op = (unsigned short*)&o;
#pragma unroll
                    for (int r = 0; r < 4; ++r) {
                        float d2 = fmaf(-2.f, acc[r], sa + sb[r]);
                        op[r] = f2bf(sqrtf(fmaxf(d2, 0.f)));
                    }
                    *reinterpret_cast<ushort4*>(slot + ldsoff + s * 32) = o;
                }
                if ((tt & 1) == 1 || tt == nt - 1) {
                    asm volatile("s_waitcnt lgkmcnt(0)" ::: "memory");
                    __builtin_amdgcn_sched_barrier(0);
                    __builtin_amdgcn_s_barrier();
                }
            }
        } else {
            // ========================= CONSUMER =========================
            const float* Drow = D + (size_t)i_row * NN;

            auto consume = [&](int tile, const f32x4(&dc)[4]) {
                const int cj = cj0 + tile * 16;
                const char* slot = &dtile[tile & 3][0];
                if (cj != q) {
#pragma unroll
                    for (int s = 0; s < 4; ++s) {
                        ushort4 o = *reinterpret_cast<const ushort4*>(slot + ldsoff + s * 32);
                        const unsigned short* op = (const unsigned short*)&o;
#pragma unroll
                        for (int r = 0; r < 4; ++r) {
                            float Dv = dc[s][r];
                            psum += __fdividef(fabsf(bf2f(op[r]) - Dv), Dv);
                        }
                    }
                } else {
#pragma unroll
                    for (int s = 0; s < 4; ++s) {
                        ushort4 o = *reinterpret_cast<const ushort4*>(slot + ldsoff + s * 32);
                        const unsigned short* op = (const unsigned short*)&o;
#pragma unroll
                        for (int r = 0; r < 4; ++r) {
                            const int j = cj * 64 + s * 16 + colq + r;
                            if (j > i_row) {
                                float Dv = dc[s][r];
                                psum += __fdividef(fabsf(bf2f(op[r]) - Dv), Dv);
                            }
                        }
                    }
                }
            };

            f32x4 dA[4], dB[4];
#pragma unroll
            for (int s = 0; s < 4; ++s)
                dA[s] = *(const f32x4*)(Drow + cj0 * 64 + s * 16 + colq);

            bool cur_a = true;
            for (int tt = 0; tt < nt; ++tt) {
                // barrier before even tiles (matches producer's per-2-tile barrier)
                if ((tt & 1) == 0) __builtin_amdgcn_s_barrier();
                const int ncj = cj0 + (tt + 1) * 16;
                if (cur_a) {
                    if (tt + 1 < nt) {
#pragma unroll
                        for (int s = 0; s < 4; ++s)
                            dB[s] = *(const f32x4*)(Drow + ncj * 64 + s * 16 + colq);
                    }
                    consume(tt, dA);
                } else {
                    if (tt + 1 < nt) {
#pragma unroll
                        for (int s = 0; s < 4; ++s)
                            dA[s] = *(const f32x4*)(Drow + ncj * 64 + s * 16 + colq);
                    }
                    consume(tt, dB);
                }
                cur_a = !cur_a;
            }
        }
    }

    // ---- deterministic block reduction (8 waves; producers contribute 0) ----
    for (int off = 32; off > 0; off >>= 1) psum += __shfl_down(psum, off, 64);
    __syncthreads();
    if (l == 0) wred[w] = psum;
    __syncthreads();
    if (t == 0) {
        float s = 0.f;
#pragma unroll
        for (int k = 0; k < 8; ++k) s += wred[k];
        partials[b] = 2.f * s;
    }
}

// ---------------------------------------------------------------------------
// Kernel 3: deterministic final reduction
// ---------------------------------------------------------------------------
__global__ void reduce_kernel(const float* __restrict__ partials, float* __restrict__ out) {
    __shared__ double sm[256];
    const int t = threadIdx.x;
    double s = 0.0;
    for (int i = t; i < NBLK; i += 256) s += (double)partials[i];
    sm[t] = s;
    __syncthreads();
    for (int off = 128; off > 0; off >>= 1) {
        if (t < off) sm[t] += sm[t + off];
        __syncthreads();
    }
    if (t == 0) out[0] = (float)(sm[0] / ((double)NN * (double)NN - (double)NN));
}

// ---------------------------------------------------------------------------
extern "C" void kernel_launch(void* const* d_in, const int* in_sizes, int n_in,
                              void* d_out, int out_size, void* d_ws, size_t ws_size,
                              hipStream_t stream) {
    const float* mapping = (const float*)d_in[0];
    const float* D       = (const float*)d_in[1];
    float* out = (float*)d_out;

    unsigned short* buf2 = (unsigned short*)d_ws;        // NN*DIM bf16 = 2 MiB
    float* sq            = (float*)(buf2 + NN * DIM);    // NN floats
    float* partials      = sq + NN;                      // NBLK floats

    pack_kernel<<<512, 256, 0, stream>>>(mapping, buf2);
    sq_kernel<<<NN / 256, 256, 0, stream>>>(mapping, sq);
    dist_kernel<<<NBLK, 512, 0, stream>>>(buf2, D, sq, partials);
    reduce_kernel<<<1, 256, 0, stream>>>(partials, out);
}